// Round 10
// baseline (259.467 us; speedup 1.0000x reference)
//
#include <hip/hip_runtime.h>

#define BATCH 32
#define TT 8
#define VOCAB 2048
#define EMB 256
#define NG 8192          // 4*VOCAB
#define LAT 128
#define KTOT 2304        // EMB + VOCAB
#define NKT 72           // K-tiles of 32
#define NNT 512          // N-tiles of 16
#define KSPLIT 8
#define KT_PER 9         // NKT/KSPLIT
#define NTHR 256

#define WSCALE 4096.0f   // weight quant scale (2^12), clip at 448 (~5.5 sigma)
#define ASCALE 16.0f     // activation quant scale (2^4)
#define DQ (1.0f/65536.0f)  // exact dequant = 1/(WSCALE*ASCALE)

typedef float f32x4 __attribute__((ext_vector_type(4)));

// ws layout (float offsets)
#define P_OFF   0
#define P_SZ    (KSPLIT*BATCH*NG)     // 8 MB partial slabs
#define H_OFF   (P_OFF + P_SZ)
#define H_SZ    (BATCH*VOCAB)
#define C_OFF   (H_OFF + H_SZ)
#define C_SZ    (BATCH*VOCAB)
#define ST_OFF  (C_OFF + C_SZ)
#define ST_SZ   (BATCH*8*2)
#define ESJ_OFF (ST_OFF + ST_SZ)
#define ESJ_SZ  32
#define AHB_OFF (ESJ_OFF + ESJ_SZ)    // uchar region: 32*2304 bytes
#define AHB_SZF ((BATCH*KTOT)/4)
#define BP_OFF  (AHB_OFF + AHB_SZF)   // uchar region: 512*72*64*8 B (~18.9MB)

__device__ __forceinline__ float sigmoidf_(float x){ return 1.f/(1.f+__expf(-x)); }
__device__ __forceinline__ float tanhf_(float x){
  x = fminf(fmaxf(x, -10.f), 10.f);
  float e = __expf(2.f*x);
  return (e-1.f)/(e+1.f);
}

// float -> OCP e4m3fn, round-to-nearest-even, saturate to 448
__device__ __forceinline__ unsigned char f2e4m3(float f){
  unsigned int u = __float_as_uint(f);
  unsigned char sign = (unsigned char)((u >> 24) & 0x80);
  float a = fabsf(f);
  if (a >= 464.f) return sign | 0x7E;          // clamp to 448
  if (a < 0.015625f){                           // denormal range (< 2^-6)
    float q = rintf(a * 512.f);                 // units of 2^-9
    if (q >= 8.f) return sign | 0x08;           // rounds up to 2^-6
    return sign | (unsigned char)q;
  }
  int e;
  float m = frexpf(a, &e);                      // a = m*2^e, m in [0.5,1)
  int E = e - 1;                                // a = (2m)*2^E, 2m in [1,2)
  float q = rintf(ldexpf(a, 3 - E));            // mant*8, in [8,16]
  int qi = (int)q;
  if (qi == 16){ qi = 8; E += 1; }
  if (E > 8) return sign | 0x7E;
  if (E == 8 && qi > 14) qi = 14;               // max finite 448 = 1.75*2^8
  return sign | (unsigned char)(((E + 7) << 3) | (qi - 8));
}

// One-time: pack [Wi;Wh]*4096 -> e4m3 in MFMA B-fragment order; init state.
// Bp[nt][kt][lane][j] = W[kt*32 + (lane>>4)*8 + j][nt*16 + (lane&15)]
__global__ __launch_bounds__(NTHR) void k_packinit(
    const int* __restrict__ tok, const float* __restrict__ E,
    const float* __restrict__ Wi, const float* __restrict__ Wh,
    unsigned long long* __restrict__ Bp, float* __restrict__ h, float* __restrict__ c,
    unsigned char* __restrict__ Ahb, float* __restrict__ out){
  const int i = blockIdx.x*NTHR + threadIdx.x;     // [0, 512*72*64)
  {
    int lane = i & 63, kt = (i>>6) % NKT, nt = i/(64*NKT);
    int n = nt*16 + (lane & 15);
    int k0 = kt*32 + (lane>>4)*8;
    unsigned long long pk = 0ull;
    #pragma unroll
    for (int p=0;p<8;p++){
      int k = k0 + p;
      float f = (k < EMB) ? Wi[(size_t)k*NG + n] : Wh[(size_t)(k-EMB)*NG + n];
      pk |= ((unsigned long long)f2e4m3(f*WSCALE)) << (8*p);
    }
    Bp[i] = pk;
  }
  if (i < BATCH*VOCAB){ h[i] = 0.f; c[i] = 0.f; }
  if (i < BATCH*KTOT){
    int b = i / KTOT, k = i % KTOT;
    Ahb[i] = (k < EMB) ? f2e4m3(ASCALE*E[(size_t)tok[b*TT+0]*EMB + k]) : (unsigned char)0;
  }
  if (i < BATCH*LAT)
    out[(size_t)((i>>7)*TT + 0)*LAT + (i&(LAT-1))] = 0.f;  // t=0: rng=0 -> z=0
}

// P[kc] = [x|h](fp8) @ [Wi;Wh](fp8 packed) k-slice, fp32 accumulate.
// Wave: M=32 x N=16 tile, 9 k-tiles, all 9 B-fragments preloaded.
// kc = blockIdx.x & 7 pins each 2.36MB Bp slice to one XCD's L2.
// Block 0 also finalizes the PREVIOUS step's output (t>=2).
__global__ __launch_bounds__(NTHR) void k_gemm(
    const unsigned char* __restrict__ Ahb, const unsigned long long* __restrict__ Bp,
    float* __restrict__ P, const float* __restrict__ stats,
    const float* __restrict__ esj, float* __restrict__ out, int t){
  const int tid = threadIdx.x;

  if (blockIdx.x==0 && t>=2){    // block-uniform branch
    __shared__ float vsh[BATCH];
    if (tid < BATCH){
      float Z=0.f, S=0.f;
      #pragma unroll
      for (int jc=0;jc<8;jc++){ Z += stats[(tid*8+jc)*2]; S += stats[(tid*8+jc)*2+1]; }
      vsh[tid] = (3.f*S + 1.5f*esj[tid])/Z;
    }
    __syncthreads();
    for (int i=tid; i<BATCH*LAT; i+=NTHR)
      out[(size_t)((i>>7)*TT + (t-1))*LAT + (i&(LAT-1))] = vsh[i>>7];
  }

  const int w = tid >> 6, lane = tid & 63;
  const int quad = lane >> 4, col = lane & 15;
  const int kc = blockIdx.x & 7;                 // XCD-pinned k-slice
  const int nt = (blockIdx.x >> 3)*4 + w;        // [0, 512)
  const int kt0 = kc*KT_PER;
  const long* __restrict__ AhV = (const long*)Ahb;   // idx m*288 + kt*4 + quad
  const long* __restrict__ BpV = (const long*)Bp;    // idx (nt*NKT+kt)*64 + lane

  long bfr[KT_PER];                              // 9 outstanding wave-loads
  #pragma unroll
  for (int i=0;i<KT_PER;i++)
    bfr[i] = BpV[((size_t)nt*NKT + kt0+i)*64 + lane];

  f32x4 acc0={0,0,0,0}, acc1={0,0,0,0};
  const int a0b = col*(KTOT/8), a1b = (16+col)*(KTOT/8);
  #pragma unroll
  for (int i=0;i<KT_PER;i++){
    long a0 = AhV[a0b + (kt0+i)*4 + quad];
    long a1 = AhV[a1b + (kt0+i)*4 + quad];
    acc0 = __builtin_amdgcn_mfma_f32_16x16x32_fp8_fp8(a0, bfr[i], acc0, 0,0,0);
    acc1 = __builtin_amdgcn_mfma_f32_16x16x32_fp8_fp8(a1, bfr[i], acc1, 0,0,0);
  }
  float* Pp = P + (size_t)kc*BATCH*NG;
  const int rowd = quad*4;
  #pragma unroll
  for (int r=0;r<4;r++){
    Pp[(size_t)(rowd+r)*NG    + nt*16 + col] = acc0[r];
    Pp[(size_t)(16+rowd+r)*NG + nt*16 + col] = acc1[r];
  }
}

// Reduce KSPLIT slabs, dequant, + bias -> gates -> masked LSTM cell -> h,c ->
// fp8 h into Ahb; jc==0 blocks stage next step's x-row; partial softmax stats.
__global__ __launch_bounds__(NTHR) void k_cellred(
    const int* __restrict__ tok, const float* __restrict__ E,
    const float* __restrict__ bias, const float* __restrict__ P,
    float* __restrict__ h, float* __restrict__ c, unsigned char* __restrict__ Ahb,
    float* __restrict__ stats, float* __restrict__ esj, int t){
  const int tid = threadIdx.x;
  const int jc = blockIdx.x, b = blockIdx.y;
  const int j = jc*256 + tid;
  const int lane = tid & 63, wid = tid >> 6;

  float ip = 0.f, fp = 0.f, gg = 0.f, op = 0.f;
  #pragma unroll
  for (int kc=0;kc<KSPLIT;kc++){
    const float* Pp = P + (size_t)(kc*BATCH + b)*NG;
    ip += Pp[j]; fp += Pp[j+VOCAB]; gg += Pp[j+2*VOCAB]; op += Pp[j+3*VOCAB];
  }
  ip = ip*DQ + bias[j];
  fp = fp*DQ + bias[j+VOCAB];
  gg = gg*DQ + bias[j+2*VOCAB];
  op = op*DQ + bias[j+3*VOCAB];

  float cold = c[b*VOCAB + j];
  float cn = sigmoidf_(fp)*cold + sigmoidf_(ip)*tanhf_(gg);
  float hn = sigmoidf_(op)*tanhf_(cn);
  const bool upd = tok[b*TT + (t-1)] != 0;
  float hf = upd ? hn : h[b*VOCAB + j];
  float cf = upd ? cn : cold;
  h[b*VOCAB + j] = hf;
  c[b*VOCAB + j] = cf;
  Ahb[b*KTOT + EMB + j] = f2e4m3(ASCALE*hf);
  if (jc == 0 && t < TT-1)   // stage next step's x-row: x = E[tok[:,t]]
    Ahb[b*KTOT + tid] = f2e4m3(ASCALE*E[(size_t)tok[b*TT + t]*EMB + tid]);

  const int sj = tok[b*TT + t];
  float e = __expf(hf);                 // h in (-1,1): no max-pass needed
  float z = e, s = (j < sj) ? e : 0.f;
  if (j == sj) esj[b] = e;

  __shared__ float zsh[4], ssh[4];
  #pragma unroll
  for (int off=32; off; off>>=1){ z += __shfl_down(z, off); s += __shfl_down(s, off); }
  if (lane==0){ zsh[wid] = z; ssh[wid] = s; }
  __syncthreads();
  if (tid==0){
    stats[(b*8 + jc)*2 + 0] = zsh[0]+zsh[1]+zsh[2]+zsh[3];
    stats[(b*8 + jc)*2 + 1] = ssh[0]+ssh[1]+ssh[2]+ssh[3];
  }
}

// z[b,t,:] = (3*S + 1.5*e_sj)/Z  broadcast over LAT  (final step)
__global__ __launch_bounds__(NTHR) void k_out(
    const float* __restrict__ stats, const float* __restrict__ esj,
    float* __restrict__ out, int t){
  const int tid = threadIdx.x;
  __shared__ float vsh[BATCH];
  if (tid < BATCH){
    float Z=0.f, S=0.f;
    #pragma unroll
    for (int jc=0;jc<8;jc++){ Z += stats[(tid*8+jc)*2]; S += stats[(tid*8+jc)*2+1]; }
    vsh[tid] = (3.f*S + 1.5f*esj[tid])/Z;
  }
  __syncthreads();
  for (int i=tid; i<BATCH*LAT; i+=NTHR)
    out[(size_t)((i>>7)*TT + t)*LAT + (i&(LAT-1))] = vsh[i>>7];
}

extern "C" void kernel_launch(void* const* d_in, const int* in_sizes, int n_in,
                              void* d_out, int out_size, void* d_ws, size_t ws_size,
                              hipStream_t stream){
  const int*   tok  = (const int*)d_in[0];
  const float* E    = (const float*)d_in[1];
  const float* Wi   = (const float*)d_in[2];
  const float* Wh   = (const float*)d_in[3];
  const float* bias = (const float*)d_in[4];
  float* out = (float*)d_out;
  float* ws  = (float*)d_ws;
  float* P     = ws + P_OFF;
  float* h     = ws + H_OFF;
  float* c     = ws + C_OFF;
  float* stats = ws + ST_OFF;
  float* esj   = ws + ESJ_OFF;
  unsigned char* Ahb = (unsigned char*)(ws + AHB_OFF);
  unsigned long long* Bp = (unsigned long long*)(ws + BP_OFF);

  k_packinit<<<(NNT*NKT*64)/NTHR, NTHR, 0, stream>>>(tok, E, Wi, Wh, Bp, h, c, Ahb, out);
  for (int t = 1; t < TT; t++){
    k_gemm<<<NNT*KSPLIT/4, NTHR, 0, stream>>>(Ahb, Bp, P, stats, esj, out, t);
    k_cellred<<<dim3(8, BATCH), NTHR, 0, stream>>>(tok, E, bias, P, h, c, Ahb, stats, esj, t);
  }
  k_out<<<1, NTHR, 0, stream>>>(stats, esj, out, TT-1);
}